// Round 4
// baseline (12246.758 us; speedup 1.0000x reference)
//
#include <hip/hip_runtime.h>

#define N_PTS 16384
#define M_PTS 4096
#define D_INF 64
#define D_OUTF 128
#define KNN 16
#define DF 67   // 3 + 64

// ---------------- squared norms of p, numpy op order ----------------
__global__ __launch_bounds__(256) void sp_kernel(const float* __restrict__ p,
                                                 float* __restrict__ spn) {
  int j = blockIdx.x * 256 + threadIdx.x;
  float a = p[3 * j], b = p[3 * j + 1], c = p[3 * j + 2];
  spn[j] = __fadd_rn(__fadd_rn(__fmul_rn(a, a), __fmul_rn(b, b)), __fmul_rn(c, c));
}

// ---------------- FPS: single block, 1024 thr x 16 pts ----------------
// amdgpu_waves_per_eu(4,4): pins occupancy to exactly 4 waves/EU (our 16-wave
// block on one CU), giving a 128-VGPR budget AND removing the allocator's
// incentive to shrink below it. R0-R3 evidence: without the max pin, the
// occupancy heuristic chose 64-124 VGPR targets and spilled the 64-float
// per-thread state to scratch every time (12-13 ms). State = 16 named float4s,
// field-only access; one barrier/iter via parity-double-buffered LDS slots.
#define FPS_T 1024
#define FPS_W (FPS_T / 64)

__global__ __launch_bounds__(FPS_T)
__attribute__((amdgpu_waves_per_eu(4, 4)))
void fps_kernel(const float* __restrict__ p,
                int* __restrict__ sidx,
                float* __restrict__ np_out) {
  const int t = threadIdx.x;
  float4 x0, x1, x2, x3, y0, y1, y2, y3, z0, z1, z2, z3, d0, d1, d2, d3;

#define FPS_LD(XV, YV, ZV, DV, K)                                   \
  do {                                                              \
    int j = t + ((K) << 10);                                        \
    XV = p[3 * j]; YV = p[3 * j + 1]; ZV = p[3 * j + 2];            \
    DV = INFINITY;                                                  \
  } while (0)

  FPS_LD(x0.x, y0.x, z0.x, d0.x, 0);
  FPS_LD(x0.y, y0.y, z0.y, d0.y, 1);
  FPS_LD(x0.z, y0.z, z0.z, d0.z, 2);
  FPS_LD(x0.w, y0.w, z0.w, d0.w, 3);
  FPS_LD(x1.x, y1.x, z1.x, d1.x, 4);
  FPS_LD(x1.y, y1.y, z1.y, d1.y, 5);
  FPS_LD(x1.z, y1.z, z1.z, d1.z, 6);
  FPS_LD(x1.w, y1.w, z1.w, d1.w, 7);
  FPS_LD(x2.x, y2.x, z2.x, d2.x, 8);
  FPS_LD(x2.y, y2.y, z2.y, d2.y, 9);
  FPS_LD(x2.z, y2.z, z2.z, d2.z, 10);
  FPS_LD(x2.w, y2.w, z2.w, d2.w, 11);
  FPS_LD(x3.x, y3.x, z3.x, d3.x, 12);
  FPS_LD(x3.y, y3.y, z3.y, d3.y, 13);
  FPS_LD(x3.z, y3.z, z3.z, d3.z, 14);
  FPS_LD(x3.w, y3.w, z3.w, d3.w, 15);

  __shared__ float s_v[2][FPS_W];
  __shared__ int   s_i[2][FPS_W];
  __shared__ float s_x[2][FPS_W], s_y[2][FPS_W], s_z[2][FPS_W];
  if (t == 0) {
    sidx[0] = 0;
    np_out[0] = p[0]; np_out[1] = p[1]; np_out[2] = p[2];
  }
  float lx = p[0], ly = p[1], lz = p[2];

  for (int i = 1; i < M_PTS; ++i) {
    float tmax = -INFINITY;
    // numpy order: ((dx*dx + dy*dy) + dz*dz), no fma contraction.
    // fminf/fmaxf chains are exactly associative/commutative (no NaNs here),
    // so evaluation order of the 16 steps doesn't affect results.
#define FPS_STEP(XV, YV, ZV, DV)                                              \
  do {                                                                        \
    float dx = __fsub_rn(XV, lx);                                             \
    float dy = __fsub_rn(YV, ly);                                             \
    float dz = __fsub_rn(ZV, lz);                                             \
    float d = __fadd_rn(__fadd_rn(__fmul_rn(dx, dx), __fmul_rn(dy, dy)),      \
                        __fmul_rn(dz, dz));                                   \
    float nd = fminf(DV, d);                                                  \
    DV = nd;                                                                  \
    tmax = fmaxf(tmax, nd);                                                   \
  } while (0)

    FPS_STEP(x0.x, y0.x, z0.x, d0.x);
    FPS_STEP(x0.y, y0.y, z0.y, d0.y);
    FPS_STEP(x0.z, y0.z, z0.z, d0.z);
    FPS_STEP(x0.w, y0.w, z0.w, d0.w);
    FPS_STEP(x1.x, y1.x, z1.x, d1.x);
    FPS_STEP(x1.y, y1.y, z1.y, d1.y);
    FPS_STEP(x1.z, y1.z, z1.z, d1.z);
    FPS_STEP(x1.w, y1.w, z1.w, d1.w);
    FPS_STEP(x2.x, y2.x, z2.x, d2.x);
    FPS_STEP(x2.y, y2.y, z2.y, d2.y);
    FPS_STEP(x2.z, y2.z, z2.z, d2.z);
    FPS_STEP(x2.w, y2.w, z2.w, d2.w);
    FPS_STEP(x3.x, y3.x, z3.x, d3.x);
    FPS_STEP(x3.y, y3.y, z3.y, d3.y);
    FPS_STEP(x3.z, y3.z, z3.z, d3.z);
    FPS_STEP(x3.w, y3.w, z3.w, d3.w);

    // smallest owned global index achieving tmax (j = t + k*1024, monotone in
    // k) -> backward scan k = 15..0, first-occurrence argmax semantics
    int ri = 0x7FFFFFFF;
    float cx = 0.f, cy = 0.f, cz = 0.f;
#define FPS_SCAN(XV, YV, ZV, DV, K)                                  \
  do {                                                               \
    if (DV == tmax) { ri = t + ((K) << 10); cx = XV; cy = YV; cz = ZV; } \
  } while (0)

    FPS_SCAN(x3.w, y3.w, z3.w, d3.w, 15);
    FPS_SCAN(x3.z, y3.z, z3.z, d3.z, 14);
    FPS_SCAN(x3.y, y3.y, z3.y, d3.y, 13);
    FPS_SCAN(x3.x, y3.x, z3.x, d3.x, 12);
    FPS_SCAN(x2.w, y2.w, z2.w, d2.w, 11);
    FPS_SCAN(x2.z, y2.z, z2.z, d2.z, 10);
    FPS_SCAN(x2.y, y2.y, z2.y, d2.y, 9);
    FPS_SCAN(x2.x, y2.x, z2.x, d2.x, 8);
    FPS_SCAN(x1.w, y1.w, z1.w, d1.w, 7);
    FPS_SCAN(x1.z, y1.z, z1.z, d1.z, 6);
    FPS_SCAN(x1.y, y1.y, z1.y, d1.y, 5);
    FPS_SCAN(x1.x, y1.x, z1.x, d1.x, 4);
    FPS_SCAN(x0.w, y0.w, z0.w, d0.w, 3);
    FPS_SCAN(x0.z, y0.z, z0.z, d0.z, 2);
    FPS_SCAN(x0.y, y0.y, z0.y, d0.y, 1);
    FPS_SCAN(x0.x, y0.x, z0.x, d0.x, 0);

    float rv = tmax;
    // wave reduce: max value, tie -> min global index (jnp.argmax first-occ.)
#pragma unroll
    for (int off = 32; off >= 1; off >>= 1) {
      float ov = __shfl_xor(rv, off);
      int   oi = __shfl_xor(ri, off);
      bool tk = (ov > rv) || (ov == rv && oi < ri);
      rv = tk ? ov : rv;
      ri = tk ? oi : ri;
    }
    // owner thread of ri has lane (ri & 63) within this wave: pull its coords
    int src = ri & 63;
    float wx = __shfl(cx, src);
    float wy = __shfl(cy, src);
    float wz = __shfl(cz, src);
    const int par = i & 1;
    if ((t & 63) == 0) {
      int w = t >> 6;
      s_v[par][w] = rv; s_i[par][w] = ri;
      s_x[par][w] = wx; s_y[par][w] = wy; s_z[par][w] = wz;
    }
    __syncthreads();  // only barrier per iteration (parity buffers avoid WAR)
    float gv = s_v[par][0];
    int   gi = s_i[par][0];
    int   gw = 0;
#pragma unroll
    for (int w = 1; w < FPS_W; ++w) {
      float ov = s_v[par][w];
      int   oi = s_i[par][w];
      bool tk = (ov > gv) || (ov == gv && oi < gi);
      gv = tk ? ov : gv;
      gi = tk ? oi : gi;
      gw = tk ? w : gw;
    }
    lx = s_x[par][gw]; ly = s_y[par][gw]; lz = s_z[par][gw];
    if (t == 0) {
      sidx[i] = gi;
      np_out[3 * i] = lx; np_out[3 * i + 1] = ly; np_out[3 * i + 2] = lz;
    }
  }
}

// ---------------- kNN + grouping + maxpool features: one wave per query ----
__global__ __launch_bounds__(256) void knn_feat_kernel(const float* __restrict__ p,
                                                       const float* __restrict__ x,
                                                       const float* __restrict__ spn,
                                                       const int* __restrict__ sidx,
                                                       float* __restrict__ feat) {
  __shared__ float cd[4][256];
  __shared__ int ci[4][256];
  __shared__ int cnt[4];
  __shared__ int s_nn[4][KNN];
  const int w = threadIdx.x >> 6;
  const int lane = threadIdx.x & 63;
  const int q = (blockIdx.x << 2) + w;
  const int qi = sidx[q];
  const float qx = p[3 * qi], qy = p[3 * qi + 1], qz = p[3 * qi + 2];
  const float sn = spn[qi];
  if (lane == 0) cnt[w] = 0;
  // Phase A: per-lane min distance over its 256 candidates
  float lmin = INFINITY;
  for (int it = 0; it < N_PTS / 64; ++it) {
    int j = lane + (it << 6);
    float dot = __fmaf_rn(qz, p[3 * j + 2],
                 __fmaf_rn(qy, p[3 * j + 1], __fmul_rn(qx, p[3 * j])));
    float d2 = __fsub_rn(__fadd_rn(sn, spn[j]), __fmul_rn(2.0f, dot));
    lmin = fminf(lmin, d2);
  }
  // tau = 16th smallest of 64 lane minima (valid upper bound on 16th NN dist)
  float mv = lmin;
  float tau = INFINITY;
#pragma unroll
  for (int r = 0; r < KNN; ++r) {
    float rmin = mv;
#pragma unroll
    for (int off = 32; off >= 1; off >>= 1) rmin = fminf(rmin, __shfl_xor(rmin, off));
    tau = rmin;
    unsigned long long msk = __ballot(mv == rmin);
    if (lane == (int)(__ffsll(msk) - 1)) mv = INFINITY;
  }
  __syncthreads();
  // Phase B: compact all candidates with d2 <= tau (expected ~18-40)
  for (int it = 0; it < N_PTS / 64; ++it) {
    int j = lane + (it << 6);
    float dot = __fmaf_rn(qz, p[3 * j + 2],
                 __fmaf_rn(qy, p[3 * j + 1], __fmul_rn(qx, p[3 * j])));
    float d2 = __fsub_rn(__fadd_rn(sn, spn[j]), __fmul_rn(2.0f, dot));
    if (d2 <= tau) {
      int pos = atomicAdd(&cnt[w], 1);
      if (pos < 256) { cd[w][pos] = d2; ci[w][pos] = j; }
    }
  }
  __syncthreads();
  // Phase C: extract 16 smallest by (value, index) — stable top_k semantics
  int C = min(cnt[w], 256);
  float vv[4]; int ii[4];
#pragma unroll
  for (int s = 0; s < 4; ++s) {
    int pos = lane + (s << 6);
    bool ok = pos < C;
    vv[s] = ok ? cd[w][pos] : INFINITY;
    ii[s] = ok ? ci[w][pos] : 0x7FFFFFFF;
  }
#pragma unroll
  for (int r = 0; r < KNN; ++r) {
    float bv = vv[0]; int bi = ii[0]; int bs = 0;
#pragma unroll
    for (int s = 1; s < 4; ++s) {
      bool tk = (vv[s] < bv) || (vv[s] == bv && ii[s] < bi);
      bv = tk ? vv[s] : bv; bi = tk ? ii[s] : bi; bs = tk ? s : bs;
    }
    float rv = bv; int ri = bi;
#pragma unroll
    for (int off = 32; off >= 1; off >>= 1) {
      float ov = __shfl_xor(rv, off); int oi = __shfl_xor(ri, off);
      bool tk = (ov < rv) || (ov == rv && oi < ri);
      rv = tk ? ov : rv; ri = tk ? oi : ri;
    }
    if (bi == ri) {  // my local-best slot won: retire it
#pragma unroll
      for (int s = 0; s < 4; ++s) if (s == bs) vv[s] = INFINITY;
    }
    if (lane == 0) s_nn[w][r] = ri;
  }
  __syncthreads();
  // Phase D: relative coords, norm scaling, maxpool
  float ax = -INFINITY, ay = -INFINITY, az = -INFINITY, nr = -INFINITY;
  if (lane < KNN) {
    int jn = s_nn[w][lane];
    ax = __fsub_rn(p[3 * jn], qx);
    ay = __fsub_rn(p[3 * jn + 1], qy);
    az = __fsub_rn(p[3 * jn + 2], qz);
    nr = sqrtf(__fadd_rn(__fadd_rn(__fmul_rn(ax, ax), __fmul_rn(ay, ay)),
                         __fmul_rn(az, az)));
  }
  float mnr = nr, mx = ax, my = ay, mz = az;
#pragma unroll
  for (int off = 32; off >= 1; off >>= 1) {
    mnr = fmaxf(mnr, __shfl_xor(mnr, off));
    mx = fmaxf(mx, __shfl_xor(mx, off));
    my = fmaxf(my, __shfl_xor(my, off));
    mz = fmaxf(mz, __shfl_xor(mz, off));
  }
  if (lane == 0) {
    // max over k commutes exactly with the (monotone) division
    float sden = __fadd_rn(mnr, 1e-8f);
    feat[q * DF + 0] = mx / sden;
    feat[q * DF + 1] = my / sden;
    feat[q * DF + 2] = mz / sden;
  }
  float fm = -INFINITY;
#pragma unroll
  for (int k = 0; k < KNN; ++k) {
    int jn = s_nn[w][k];
    fm = fmaxf(fm, x[(jn << 6) + lane]);
  }
  feat[q * DF + 3 + lane] = fm;
}

// ---------------- MLP: h = feat @ W + b ----------------
__global__ __launch_bounds__(128) void mlp_kernel(const float* __restrict__ feat,
                                                  const float* __restrict__ W,
                                                  const float* __restrict__ b,
                                                  float* __restrict__ h) {
  int mrow = blockIdx.x;
  int o = threadIdx.x;
  const float* fr = feat + mrow * DF;
  float acc = b[o];
#pragma unroll
  for (int k = 0; k < DF; ++k) acc = __fmaf_rn(fr[k], W[k * D_OUTF + o], acc);
  h[mrow * D_OUTF + o] = acc;
}

// ---------------- BN column stats (training mode) ----------------
__global__ __launch_bounds__(256) void stats_kernel(const float* __restrict__ h,
                                                    const float* __restrict__ gamma,
                                                    const float* __restrict__ beta,
                                                    float* __restrict__ scsh) {
  int o = blockIdx.x;
  int t = threadIdx.x;
  float s = 0.f, s2 = 0.f;
  for (int mrow = t; mrow < M_PTS; mrow += 256) {
    float v = h[mrow * D_OUTF + o];
    s += v;
    s2 = __fmaf_rn(v, v, s2);
  }
#pragma unroll
  for (int off = 32; off >= 1; off >>= 1) {
    s += __shfl_xor(s, off);
    s2 += __shfl_xor(s2, off);
  }
  __shared__ float as1[4], as2[4];
  if ((t & 63) == 0) { as1[t >> 6] = s; as2[t >> 6] = s2; }
  __syncthreads();
  if (t == 0) {
    float ts = ((as1[0] + as1[1]) + as1[2]) + as1[3];
    float ts2 = ((as2[0] + as2[1]) + as2[2]) + as2[3];
    float mean = ts / (float)M_PTS;
    float var = ts2 / (float)M_PTS - mean * mean;
    var = fmaxf(var, 0.f);
    float sc = gamma[o] / sqrtf(var + 1e-5f);
    scsh[o] = sc;
    scsh[D_OUTF + o] = beta[o] - mean * sc;
  }
}

// ---------------- BN apply + ReLU + n_o ----------------
__global__ __launch_bounds__(256) void bn_kernel(const float* __restrict__ h,
                                                 const float* __restrict__ scsh,
                                                 float* __restrict__ out) {
  int idx = blockIdx.x * 256 + threadIdx.x;
  int o = idx & (D_OUTF - 1);
  float v = __fmaf_rn(h[idx], scsh[o], scsh[D_OUTF + o]);
  out[M_PTS * 3 + idx] = fmaxf(v, 0.f);
  if (idx == 0) out[M_PTS * 3 + M_PTS * D_OUTF] = 4096.0f;  // n_o
}

extern "C" void kernel_launch(void* const* d_in, const int* in_sizes, int n_in,
                              void* d_out, int out_size, void* d_ws, size_t ws_size,
                              hipStream_t stream) {
  const float* p     = (const float*)d_in[0];
  const float* x     = (const float*)d_in[1];
  // d_in[2] = o (offsets) — unused, single cloud
  const float* W     = (const float*)d_in[3];
  const float* b     = (const float*)d_in[4];
  const float* gamma = (const float*)d_in[5];
  const float* beta  = (const float*)d_in[6];
  float* out = (float*)d_out;

  float* wsf  = (float*)d_ws;
  int*   sidx = (int*)d_ws;                    // [4096]
  float* spn  = wsf + 4096;                    // [16384]
  float* feat = spn + N_PTS;                   // [4096 * 67]
  float* h    = feat + M_PTS * DF;             // [4096 * 128]
  float* scsh = h + M_PTS * D_OUTF;            // [256]

  sp_kernel<<<N_PTS / 256, 256, 0, stream>>>(p, spn);
  fps_kernel<<<1, FPS_T, 0, stream>>>(p, sidx, out);
  knn_feat_kernel<<<M_PTS / 4, 256, 0, stream>>>(p, x, spn, sidx, feat);
  mlp_kernel<<<M_PTS, D_OUTF, 0, stream>>>(feat, W, b, h);
  stats_kernel<<<D_OUTF, 256, 0, stream>>>(h, gamma, beta, scsh);
  bn_kernel<<<(M_PTS * D_OUTF) / 256, 256, 0, stream>>>(h, scsh, out);
}

// Round 5
// 11977.163 us; speedup vs baseline: 1.0225x; 1.0225x over previous
//
#include <hip/hip_runtime.h>

#define N_PTS 16384
#define M_PTS 4096
#define D_INF 64
#define D_OUTF 128
#define KNN 16
#define DF 67   // 3 + 64

// ---------------- squared norms of p, numpy op order ----------------
__global__ __launch_bounds__(256) void sp_kernel(const float* __restrict__ p,
                                                 float* __restrict__ spn) {
  int j = blockIdx.x * 256 + threadIdx.x;
  float a = p[3 * j], b = p[3 * j + 1], c = p[3 * j + 2];
  spn[j] = __fadd_rn(__fadd_rn(__fmul_rn(a, a), __fmul_rn(b, b)), __fmul_rn(c, c));
}

// ---------------- FPS: single block, xy in LDS, z+dd in regs ----------------
// R0-R4 lesson: any >=64-float per-thread state gets demoted (scratch or AGPR
// mov-pairs; VGPR_Count 64-124, active-CU VALU 79% issuing spill movs, ~3us/
// iter). Fix by construction: x,y live in LDS (16384*8B = 128KB, read-only
// after init, separate pipe), only z + dd stay in registers = 32 floats, which
// fits even a 64-VGPR allocation. Argmax folded into the update (strict > =
// first-occurrence); one barrier/iter via parity-double-buffered LDS slots.
#define FPS_T 1024
#define FPS_W (FPS_T / 64)

__global__ __launch_bounds__(FPS_T) void fps_kernel(const float* __restrict__ p,
                                                    int* __restrict__ sidx,
                                                    float* __restrict__ np_out) {
  const int t = threadIdx.x;
  __shared__ float2 s_xy[N_PTS];                 // 128 KB
  __shared__ float s_v[2][FPS_W];
  __shared__ int   s_i[2][FPS_W];
  __shared__ float s_z[2][FPS_W];
  float4 z0, z1, z2, z3, d0, d1, d2, d3;

#define FPS_LD(ZV, DV, K)                                            \
  do {                                                               \
    int j = t + ((K) << 10);                                         \
    float xx = p[3 * j], yy = p[3 * j + 1];                          \
    ZV = p[3 * j + 2];                                               \
    s_xy[j] = make_float2(xx, yy);                                   \
    DV = INFINITY;                                                   \
  } while (0)

  FPS_LD(z0.x, d0.x, 0);  FPS_LD(z0.y, d0.y, 1);
  FPS_LD(z0.z, d0.z, 2);  FPS_LD(z0.w, d0.w, 3);
  FPS_LD(z1.x, d1.x, 4);  FPS_LD(z1.y, d1.y, 5);
  FPS_LD(z1.z, d1.z, 6);  FPS_LD(z1.w, d1.w, 7);
  FPS_LD(z2.x, d2.x, 8);  FPS_LD(z2.y, d2.y, 9);
  FPS_LD(z2.z, d2.z, 10); FPS_LD(z2.w, d2.w, 11);
  FPS_LD(z3.x, d3.x, 12); FPS_LD(z3.y, d3.y, 13);
  FPS_LD(z3.z, d3.z, 14); FPS_LD(z3.w, d3.w, 15);

  if (t == 0) {
    sidx[0] = 0;
    np_out[0] = p[0]; np_out[1] = p[1]; np_out[2] = p[2];
  }
  float lx = p[0], ly = p[1], lz = p[2];
  __syncthreads();  // all xy visible before first full pass

  for (int i = 1; i < M_PTS; ++i) {
    float tmax = -INFINITY;
    int   bj = 0x7FFFFFFF;
    float bz = 0.f;
    // numpy order: ((dx*dx + dy*dy) + dz*dz), no fma contraction.
    // Strict '>' keeps the earliest owned j on ties (j = t + k*1024 is
    // monotone in k) -> first-occurrence argmax within a thread.
#define FPS_STEP(ZV, DV, K)                                                   \
  do {                                                                        \
    int j = t + ((K) << 10);                                                  \
    float2 xy = s_xy[j];                                                      \
    float dx = __fsub_rn(xy.x, lx);                                           \
    float dy = __fsub_rn(xy.y, ly);                                           \
    float dz = __fsub_rn(ZV, lz);                                             \
    float d = __fadd_rn(__fadd_rn(__fmul_rn(dx, dx), __fmul_rn(dy, dy)),      \
                        __fmul_rn(dz, dz));                                   \
    float nd = fminf(DV, d);                                                  \
    DV = nd;                                                                  \
    bool gt = nd > tmax;                                                      \
    tmax = gt ? nd : tmax;                                                    \
    bj = gt ? j : bj;                                                         \
    bz = gt ? ZV : bz;                                                        \
  } while (0)

    FPS_STEP(z0.x, d0.x, 0);  FPS_STEP(z0.y, d0.y, 1);
    FPS_STEP(z0.z, d0.z, 2);  FPS_STEP(z0.w, d0.w, 3);
    FPS_STEP(z1.x, d1.x, 4);  FPS_STEP(z1.y, d1.y, 5);
    FPS_STEP(z1.z, d1.z, 6);  FPS_STEP(z1.w, d1.w, 7);
    FPS_STEP(z2.x, d2.x, 8);  FPS_STEP(z2.y, d2.y, 9);
    FPS_STEP(z2.z, d2.z, 10); FPS_STEP(z2.w, d2.w, 11);
    FPS_STEP(z3.x, d3.x, 12); FPS_STEP(z3.y, d3.y, 13);
    FPS_STEP(z3.z, d3.z, 14); FPS_STEP(z3.w, d3.w, 15);

    float rv = tmax;
    int   ri = bj;
    float rz = bz;
    // wave reduce: max value, tie -> min global index (jnp.argmax first-occ.)
#pragma unroll
    for (int off = 32; off >= 1; off >>= 1) {
      float ov = __shfl_xor(rv, off);
      int   oi = __shfl_xor(ri, off);
      float oz = __shfl_xor(rz, off);
      bool tk = (ov > rv) || (ov == rv && oi < ri);
      rv = tk ? ov : rv;
      ri = tk ? oi : ri;
      rz = tk ? oz : rz;
    }
    const int par = i & 1;
    if ((t & 63) == 0) {
      int w = t >> 6;
      s_v[par][w] = rv; s_i[par][w] = ri; s_z[par][w] = rz;
    }
    __syncthreads();  // only barrier per iteration (parity buffers avoid WAR)
    float gv = s_v[par][0];
    int   gi = s_i[par][0];
    int   gw = 0;
#pragma unroll
    for (int w = 1; w < FPS_W; ++w) {
      float ov = s_v[par][w];
      int   oi = s_i[par][w];
      bool tk = (ov > gv) || (ov == gv && oi < gi);
      gv = tk ? ov : gv;
      gi = tk ? oi : gi;
      gw = tk ? w : gw;
    }
    lz = s_z[par][gw];
    float2 wxy = s_xy[gi];  // uniform address -> LDS broadcast
    lx = wxy.x; ly = wxy.y;
    if (t == 0) {
      sidx[i] = gi;
      np_out[3 * i] = lx; np_out[3 * i + 1] = ly; np_out[3 * i + 2] = lz;
    }
  }
}

// ---------------- kNN + grouping + maxpool features: one wave per query ----
__global__ __launch_bounds__(256) void knn_feat_kernel(const float* __restrict__ p,
                                                       const float* __restrict__ x,
                                                       const float* __restrict__ spn,
                                                       const int* __restrict__ sidx,
                                                       float* __restrict__ feat) {
  __shared__ float cd[4][256];
  __shared__ int ci[4][256];
  __shared__ int cnt[4];
  __shared__ int s_nn[4][KNN];
  const int w = threadIdx.x >> 6;
  const int lane = threadIdx.x & 63;
  const int q = (blockIdx.x << 2) + w;
  const int qi = sidx[q];
  const float qx = p[3 * qi], qy = p[3 * qi + 1], qz = p[3 * qi + 2];
  const float sn = spn[qi];
  if (lane == 0) cnt[w] = 0;
  // Phase A: per-lane min distance over its 256 candidates
  float lmin = INFINITY;
  for (int it = 0; it < N_PTS / 64; ++it) {
    int j = lane + (it << 6);
    float dot = __fmaf_rn(qz, p[3 * j + 2],
                 __fmaf_rn(qy, p[3 * j + 1], __fmul_rn(qx, p[3 * j])));
    float d2 = __fsub_rn(__fadd_rn(sn, spn[j]), __fmul_rn(2.0f, dot));
    lmin = fminf(lmin, d2);
  }
  // tau = 16th smallest of 64 lane minima (valid upper bound on 16th NN dist)
  float mv = lmin;
  float tau = INFINITY;
#pragma unroll
  for (int r = 0; r < KNN; ++r) {
    float rmin = mv;
#pragma unroll
    for (int off = 32; off >= 1; off >>= 1) rmin = fminf(rmin, __shfl_xor(rmin, off));
    tau = rmin;
    unsigned long long msk = __ballot(mv == rmin);
    if (lane == (int)(__ffsll(msk) - 1)) mv = INFINITY;
  }
  __syncthreads();
  // Phase B: compact all candidates with d2 <= tau (expected ~18-40)
  for (int it = 0; it < N_PTS / 64; ++it) {
    int j = lane + (it << 6);
    float dot = __fmaf_rn(qz, p[3 * j + 2],
                 __fmaf_rn(qy, p[3 * j + 1], __fmul_rn(qx, p[3 * j])));
    float d2 = __fsub_rn(__fadd_rn(sn, spn[j]), __fmul_rn(2.0f, dot));
    if (d2 <= tau) {
      int pos = atomicAdd(&cnt[w], 1);
      if (pos < 256) { cd[w][pos] = d2; ci[w][pos] = j; }
    }
  }
  __syncthreads();
  // Phase C: extract 16 smallest by (value, index) — stable top_k semantics
  int C = min(cnt[w], 256);
  float vv[4]; int ii[4];
#pragma unroll
  for (int s = 0; s < 4; ++s) {
    int pos = lane + (s << 6);
    bool ok = pos < C;
    vv[s] = ok ? cd[w][pos] : INFINITY;
    ii[s] = ok ? ci[w][pos] : 0x7FFFFFFF;
  }
#pragma unroll
  for (int r = 0; r < KNN; ++r) {
    float bv = vv[0]; int bi = ii[0]; int bs = 0;
#pragma unroll
    for (int s = 1; s < 4; ++s) {
      bool tk = (vv[s] < bv) || (vv[s] == bv && ii[s] < bi);
      bv = tk ? vv[s] : bv; bi = tk ? ii[s] : bi; bs = tk ? s : bs;
    }
    float rv = bv; int ri = bi;
#pragma unroll
    for (int off = 32; off >= 1; off >>= 1) {
      float ov = __shfl_xor(rv, off); int oi = __shfl_xor(ri, off);
      bool tk = (ov < rv) || (ov == rv && oi < ri);
      rv = tk ? ov : rv; ri = tk ? oi : ri;
    }
    if (bi == ri) {  // my local-best slot won: retire it
#pragma unroll
      for (int s = 0; s < 4; ++s) if (s == bs) vv[s] = INFINITY;
    }
    if (lane == 0) s_nn[w][r] = ri;
  }
  __syncthreads();
  // Phase D: relative coords, norm scaling, maxpool
  float ax = -INFINITY, ay = -INFINITY, az = -INFINITY, nr = -INFINITY;
  if (lane < KNN) {
    int jn = s_nn[w][lane];
    ax = __fsub_rn(p[3 * jn], qx);
    ay = __fsub_rn(p[3 * jn + 1], qy);
    az = __fsub_rn(p[3 * jn + 2], qz);
    nr = sqrtf(__fadd_rn(__fadd_rn(__fmul_rn(ax, ax), __fmul_rn(ay, ay)),
                         __fmul_rn(az, az)));
  }
  float mnr = nr, mx = ax, my = ay, mz = az;
#pragma unroll
  for (int off = 32; off >= 1; off >>= 1) {
    mnr = fmaxf(mnr, __shfl_xor(mnr, off));
    mx = fmaxf(mx, __shfl_xor(mx, off));
    my = fmaxf(my, __shfl_xor(my, off));
    mz = fmaxf(mz, __shfl_xor(mz, off));
  }
  if (lane == 0) {
    // max over k commutes exactly with the (monotone) division
    float sden = __fadd_rn(mnr, 1e-8f);
    feat[q * DF + 0] = mx / sden;
    feat[q * DF + 1] = my / sden;
    feat[q * DF + 2] = mz / sden;
  }
  float fm = -INFINITY;
#pragma unroll
  for (int k = 0; k < KNN; ++k) {
    int jn = s_nn[w][k];
    fm = fmaxf(fm, x[(jn << 6) + lane]);
  }
  feat[q * DF + 3 + lane] = fm;
}

// ---------------- MLP: h = feat @ W + b ----------------
__global__ __launch_bounds__(128) void mlp_kernel(const float* __restrict__ feat,
                                                  const float* __restrict__ W,
                                                  const float* __restrict__ b,
                                                  float* __restrict__ h) {
  int mrow = blockIdx.x;
  int o = threadIdx.x;
  const float* fr = feat + mrow * DF;
  float acc = b[o];
#pragma unroll
  for (int k = 0; k < DF; ++k) acc = __fmaf_rn(fr[k], W[k * D_OUTF + o], acc);
  h[mrow * D_OUTF + o] = acc;
}

// ---------------- BN column stats (training mode) ----------------
__global__ __launch_bounds__(256) void stats_kernel(const float* __restrict__ h,
                                                    const float* __restrict__ gamma,
                                                    const float* __restrict__ beta,
                                                    float* __restrict__ scsh) {
  int o = blockIdx.x;
  int t = threadIdx.x;
  float s = 0.f, s2 = 0.f;
  for (int mrow = t; mrow < M_PTS; mrow += 256) {
    float v = h[mrow * D_OUTF + o];
    s += v;
    s2 = __fmaf_rn(v, v, s2);
  }
#pragma unroll
  for (int off = 32; off >= 1; off >>= 1) {
    s += __shfl_xor(s, off);
    s2 += __shfl_xor(s2, off);
  }
  __shared__ float as1[4], as2[4];
  if ((t & 63) == 0) { as1[t >> 6] = s; as2[t >> 6] = s2; }
  __syncthreads();
  if (t == 0) {
    float ts = ((as1[0] + as1[1]) + as1[2]) + as1[3];
    float ts2 = ((as2[0] + as2[1]) + as2[2]) + as2[3];
    float mean = ts / (float)M_PTS;
    float var = ts2 / (float)M_PTS - mean * mean;
    var = fmaxf(var, 0.f);
    float sc = gamma[o] / sqrtf(var + 1e-5f);
    scsh[o] = sc;
    scsh[D_OUTF + o] = beta[o] - mean * sc;
  }
}

// ---------------- BN apply + ReLU + n_o ----------------
__global__ __launch_bounds__(256) void bn_kernel(const float* __restrict__ h,
                                                 const float* __restrict__ scsh,
                                                 float* __restrict__ out) {
  int idx = blockIdx.x * 256 + threadIdx.x;
  int o = idx & (D_OUTF - 1);
  float v = __fmaf_rn(h[idx], scsh[o], scsh[D_OUTF + o]);
  out[M_PTS * 3 + idx] = fmaxf(v, 0.f);
  if (idx == 0) out[M_PTS * 3 + M_PTS * D_OUTF] = 4096.0f;  // n_o
}

extern "C" void kernel_launch(void* const* d_in, const int* in_sizes, int n_in,
                              void* d_out, int out_size, void* d_ws, size_t ws_size,
                              hipStream_t stream) {
  const float* p     = (const float*)d_in[0];
  const float* x     = (const float*)d_in[1];
  // d_in[2] = o (offsets) — unused, single cloud
  const float* W     = (const float*)d_in[3];
  const float* b     = (const float*)d_in[4];
  const float* gamma = (const float*)d_in[5];
  const float* beta  = (const float*)d_in[6];
  float* out = (float*)d_out;

  float* wsf  = (float*)d_ws;
  int*   sidx = (int*)d_ws;                    // [4096]
  float* spn  = wsf + 4096;                    // [16384]
  float* feat = spn + N_PTS;                   // [4096 * 67]
  float* h    = feat + M_PTS * DF;             // [4096 * 128]
  float* scsh = h + M_PTS * D_OUTF;            // [256]

  sp_kernel<<<N_PTS / 256, 256, 0, stream>>>(p, spn);
  fps_kernel<<<1, FPS_T, 0, stream>>>(p, sidx, out);
  knn_feat_kernel<<<M_PTS / 4, 256, 0, stream>>>(p, x, spn, sidx, feat);
  mlp_kernel<<<M_PTS, D_OUTF, 0, stream>>>(feat, W, b, h);
  stats_kernel<<<D_OUTF, 256, 0, stream>>>(h, gamma, beta, scsh);
  bn_kernel<<<(M_PTS * D_OUTF) / 256, 256, 0, stream>>>(h, scsh, out);
}